// Round 1
// baseline (676.620 us; speedup 1.0000x reference)
//
#include <hip/hip_runtime.h>

#define L 512
#define D 768

// ---------------- GEMM: C = A[MxK] @ W[KxN] + bias (+ optional addend) --------
// 64x64 tile, BK=16, 256 threads, 4x4 per thread. blockIdx.z selects weight set
// (used to fuse the Q and K projections into one launch).
template<bool ADD>
__global__ __launch_bounds__(256) void gemm64(
    const float* __restrict__ A,
    const float* __restrict__ W0, const float* __restrict__ b0, float* __restrict__ C0,
    const float* __restrict__ W1, const float* __restrict__ b1, float* __restrict__ C1,
    const float* __restrict__ addend,
    int M, int N, int K)
{
    const float* Wm   = blockIdx.z ? W1 : W0;
    const float* bias = blockIdx.z ? b1 : b0;
    float*       C    = blockIdx.z ? C1 : C0;

    __shared__ float As[16][64];   // [kk][m] — transposed so per-thread rows are contiguous
    __shared__ float Bs[16][64];   // [kk][n]

    const int tid = threadIdx.x;
    const int tx = tid & 15, ty = tid >> 4;
    const int bx = blockIdx.x, by = blockIdx.y;

    float acc[4][4] = {};

    for (int k0 = 0; k0 < K; k0 += 16) {
        #pragma unroll
        for (int i = 0; i < 4; ++i) {
            int idx = tid + 256 * i;          // 0..1023
            int m  = idx >> 4;                // 0..63
            int kk = idx & 15;
            As[kk][m] = A[(by * 64 + m) * K + k0 + kk];
        }
        #pragma unroll
        for (int i = 0; i < 4; ++i) {
            int idx = tid + 256 * i;
            int kk = idx >> 6;                // 0..15
            int n  = idx & 63;
            Bs[kk][n] = Wm[(k0 + kk) * N + bx * 64 + n];
        }
        __syncthreads();
        #pragma unroll
        for (int kk = 0; kk < 16; ++kk) {
            float4 a = *(const float4*)&As[kk][ty * 4];
            float4 b = *(const float4*)&Bs[kk][tx * 4];
            float av[4] = {a.x, a.y, a.z, a.w};
            float bv[4] = {b.x, b.y, b.z, b.w};
            #pragma unroll
            for (int i = 0; i < 4; ++i)
                #pragma unroll
                for (int j = 0; j < 4; ++j)
                    acc[i][j] = fmaf(av[i], bv[j], acc[i][j]);
        }
        __syncthreads();
    }

    #pragma unroll
    for (int i = 0; i < 4; ++i) {
        int row = by * 64 + ty * 4 + i;
        #pragma unroll
        for (int j = 0; j < 4; ++j) {
            int col = bx * 64 + tx * 4 + j;
            float v = acc[i][j] + bias[col];
            if (ADD) v += addend[row * N + col];
            C[row * N + col] = v;
        }
    }
}

// ---------------- scores + softmax + weighted = probs @ X ---------------------
// One block (256 threads = 4 waves) per query row q.
// Phase 1: each wave computes score(q,k) for k = wave, wave+4, ... with lanes
//          split over d (12 elems/lane), shuffle-reduced.
// Phase 2: block softmax over the 512 scores in LDS.
// Phase 3: weighted[q,d] = sum_k p[k] * X[k,d], coalesced row reads of X.
__global__ __launch_bounds__(256) void attn_scores(
    const float* __restrict__ Qb, const float* __restrict__ Kb,
    const float* __restrict__ X,  const float* __restrict__ mask,
    const float* __restrict__ w_att, const float* __restrict__ b_att,
    float* __restrict__ Wout)
{
    __shared__ float q_s[D];
    __shared__ float w_s[D];
    __shared__ float sc[L];
    __shared__ float red[4];

    const int q = blockIdx.x;
    const int tid = threadIdx.x;
    const int lane = tid & 63, wave = tid >> 6;

    for (int i = tid; i < D; i += 256) { q_s[i] = Qb[q * D + i]; w_s[i] = w_att[i]; }
    __syncthreads();

    const float batt = b_att[0];
    for (int k = wave; k < L; k += 4) {
        const float* Kr = Kb + k * D;
        float s = 0.f;
        #pragma unroll
        for (int j = 0; j < 12; ++j) {
            int d = lane + 64 * j;
            s = fmaf(w_s[d], tanhf(q_s[d] + Kr[d]), s);
        }
        #pragma unroll
        for (int off = 32; off; off >>= 1) s += __shfl_xor(s, off);
        if (lane == 0) sc[k] = s + batt + mask[k];
    }
    __syncthreads();

    // block max
    float m = -1e30f;
    for (int i = tid; i < L; i += 256) m = fmaxf(m, sc[i]);
    #pragma unroll
    for (int off = 32; off; off >>= 1) m = fmaxf(m, __shfl_xor(m, off));
    if (lane == 0) red[wave] = m;
    __syncthreads();
    m = fmaxf(fmaxf(red[0], red[1]), fmaxf(red[2], red[3]));
    __syncthreads();  // protect red[] before reuse

    // exp + sum
    float sum = 0.f;
    for (int i = tid; i < L; i += 256) { float e = __expf(sc[i] - m); sc[i] = e; sum += e; }
    #pragma unroll
    for (int off = 32; off; off >>= 1) sum += __shfl_xor(sum, off);
    if (lane == 0) red[wave] = sum;
    __syncthreads();
    const float inv = 1.f / (red[0] + red[1] + red[2] + red[3]);

    // weighted = p @ X ; 256 threads cover 768 cols with 3 accumulators
    float a0 = 0.f, a1 = 0.f, a2 = 0.f;
    for (int k = 0; k < L; ++k) {
        float p = sc[k];
        const float* Xr = X + k * D;
        a0 = fmaf(p, Xr[tid      ], a0);
        a1 = fmaf(p, Xr[tid + 256], a1);
        a2 = fmaf(p, Xr[tid + 512], a2);
    }
    float* Wr = Wout + q * D;
    Wr[tid      ] = a0 * inv;
    Wr[tid + 256] = a1 * inv;
    Wr[tid + 512] = a2 * inv;
}

extern "C" void kernel_launch(void* const* d_in, const int* in_sizes, int n_in,
                              void* d_out, int out_size, void* d_ws, size_t ws_size,
                              hipStream_t stream) {
    const float* X     = (const float*)d_in[0];
    const float* mask  = (const float*)d_in[1];
    const float* Wq    = (const float*)d_in[2];
    const float* bq    = (const float*)d_in[3];
    const float* Wk    = (const float*)d_in[4];
    const float* bk    = (const float*)d_in[5];
    const float* w_att = (const float*)d_in[6];
    const float* b_att = (const float*)d_in[7];
    const float* Wt    = (const float*)d_in[8];
    const float* bt    = (const float*)d_in[9];
    float* out = (float*)d_out;

    float* Qb = (float*)d_ws;          // [L*D]
    float* Kb = Qb + L * D;            // [L*D]
    float* Wb = Kb + L * D;            // [L*D] weighted

    // Q = X@Wq + bq ; K = X@Wk + bk   (fused via blockIdx.z)
    gemm64<false><<<dim3(D / 64, L / 64, 2), 256, 0, stream>>>(
        X, Wq, bq, Qb, Wk, bk, Kb, nullptr, L, D, D);

    // scores -> softmax -> weighted
    attn_scores<<<dim3(L), 256, 0, stream>>>(Qb, Kb, X, mask, w_att, b_att, Wb);

    // out = weighted@Wt + bt + Q
    gemm64<true><<<dim3(D / 64, L / 64, 1), 256, 0, stream>>>(
        Wb, Wt, bt, out, Wt, bt, out, Qb, L, D, D);
}

// Round 2
// 320.479 us; speedup vs baseline: 2.1113x; 2.1113x over previous
//
#include <hip/hip_runtime.h>

#define L 512
#define D 768

// ---------------- GEMM: C = (A[MxK] @ W[KxN] + bias)*scale (+ optional addend)
// 64x64 tile, BK=16, 256 threads, 4x4 per thread. blockIdx.z selects weight set
// (fuses the Q and K projections; K output is pre-scaled by 2 for the tanh trick).
template<bool ADD>
__global__ __launch_bounds__(256) void gemm64(
    const float* __restrict__ A,
    const float* __restrict__ W0, const float* __restrict__ b0, float* __restrict__ C0,
    const float* __restrict__ W1, const float* __restrict__ b1, float* __restrict__ C1,
    const float* __restrict__ addend,
    int M, int N, int K, float sc0, float sc1)
{
    const float* Wm   = blockIdx.z ? W1 : W0;
    const float* bias = blockIdx.z ? b1 : b0;
    float*       C    = blockIdx.z ? C1 : C0;
    const float  scale = blockIdx.z ? sc1 : sc0;

    __shared__ float As[16][64];   // [kk][m]
    __shared__ float Bs[16][64];   // [kk][n]

    const int tid = threadIdx.x;
    const int tx = tid & 15, ty = tid >> 4;
    const int bx = blockIdx.x, by = blockIdx.y;

    float acc[4][4] = {};

    for (int k0 = 0; k0 < K; k0 += 16) {
        #pragma unroll
        for (int i = 0; i < 4; ++i) {
            int idx = tid + 256 * i;
            int m  = idx >> 4;
            int kk = idx & 15;
            As[kk][m] = A[(by * 64 + m) * K + k0 + kk];
        }
        #pragma unroll
        for (int i = 0; i < 4; ++i) {
            int idx = tid + 256 * i;
            int kk = idx >> 6;
            int n  = idx & 63;
            Bs[kk][n] = Wm[(k0 + kk) * N + bx * 64 + n];
        }
        __syncthreads();
        #pragma unroll
        for (int kk = 0; kk < 16; ++kk) {
            float4 a = *(const float4*)&As[kk][ty * 4];
            float4 b = *(const float4*)&Bs[kk][tx * 4];
            float av[4] = {a.x, a.y, a.z, a.w};
            float bv[4] = {b.x, b.y, b.z, b.w};
            #pragma unroll
            for (int i = 0; i < 4; ++i)
                #pragma unroll
                for (int j = 0; j < 4; ++j)
                    acc[i][j] = fmaf(av[i], bv[j], acc[i][j]);
        }
        __syncthreads();
    }

    #pragma unroll
    for (int i = 0; i < 4; ++i) {
        int row = by * 64 + ty * 4 + i;
        #pragma unroll
        for (int j = 0; j < 4; ++j) {
            int col = bx * 64 + tx * 4 + j;
            float v = (acc[i][j] + bias[col]) * scale;
            if (ADD) v += addend[row * N + col];
            C[row * N + col] = v;
        }
    }
}

// ---------------- scores + softmax + weighted = probs @ X ---------------------
// One block (256 threads = 4 waves) per query row q.
// tanh(x) = 1 - 2/(e^{2x}+1);  sum_d w*tanh(q+k) = Wsum - 2*sum_d w/(e^{2q+2k}+1).
// Kb holds 2*(X@Wk+bk) (pre-scaled in the GEMM); q is scaled by 2 at load.
// Each lane owns d = lane + 64*j, j=0..11 -> q,w live in registers.
__global__ __launch_bounds__(256) void attn_scores(
    const float* __restrict__ Qb, const float* __restrict__ Kb2,
    const float* __restrict__ X,  const float* __restrict__ mask,
    const float* __restrict__ w_att, const float* __restrict__ b_att,
    float* __restrict__ Wout)
{
    __shared__ float sc[L];
    __shared__ float red[4];

    const int q = blockIdx.x;
    const int tid = threadIdx.x;
    const int lane = tid & 63, wave = tid >> 6;

    // per-lane q (x2) and w in registers; Wsum = sum of this lane's w
    float qv[12], wv[12];
    float Wsum = 0.f;
    #pragma unroll
    for (int j = 0; j < 12; ++j) {
        int d = lane + 64 * j;
        qv[j] = 2.f * Qb[q * D + d];
        wv[j] = w_att[d];
        Wsum += wv[j];
    }

    const float batt = b_att[0];
    #pragma unroll 2
    for (int k = wave; k < L; k += 4) {
        const float* Kr = Kb2 + k * D;
        float acc = 0.f;
        #pragma unroll
        for (int j = 0; j < 12; ++j) {
            float t = __expf(qv[j] + Kr[lane + 64 * j]);
            acc += __fdividef(wv[j], t + 1.f);
        }
        float s = Wsum - 2.f * acc;
        #pragma unroll
        for (int off = 32; off; off >>= 1) s += __shfl_xor(s, off);
        if (lane == 0) sc[k] = s + batt + mask[k];
    }
    __syncthreads();

    // block max
    float m = -1e30f;
    for (int i = tid; i < L; i += 256) m = fmaxf(m, sc[i]);
    #pragma unroll
    for (int off = 32; off; off >>= 1) m = fmaxf(m, __shfl_xor(m, off));
    if (lane == 0) red[wave] = m;
    __syncthreads();
    m = fmaxf(fmaxf(red[0], red[1]), fmaxf(red[2], red[3]));
    __syncthreads();

    // exp + sum
    float sum = 0.f;
    for (int i = tid; i < L; i += 256) { float e = __expf(sc[i] - m); sc[i] = e; sum += e; }
    #pragma unroll
    for (int off = 32; off; off >>= 1) sum += __shfl_xor(sum, off);
    if (lane == 0) red[wave] = sum;
    __syncthreads();
    const float inv = 1.f / (red[0] + red[1] + red[2] + red[3]);

    // weighted = p @ X ; 256 threads cover 768 cols with 3 accumulators
    float a0 = 0.f, a1 = 0.f, a2 = 0.f;
    #pragma unroll 4
    for (int k = 0; k < L; ++k) {
        float p = sc[k];
        const float* Xr = X + k * D;
        a0 = fmaf(p, Xr[tid      ], a0);
        a1 = fmaf(p, Xr[tid + 256], a1);
        a2 = fmaf(p, Xr[tid + 512], a2);
    }
    float* Wr = Wout + q * D;
    Wr[tid      ] = a0 * inv;
    Wr[tid + 256] = a1 * inv;
    Wr[tid + 512] = a2 * inv;
}

extern "C" void kernel_launch(void* const* d_in, const int* in_sizes, int n_in,
                              void* d_out, int out_size, void* d_ws, size_t ws_size,
                              hipStream_t stream) {
    const float* X     = (const float*)d_in[0];
    const float* mask  = (const float*)d_in[1];
    const float* Wq    = (const float*)d_in[2];
    const float* bq    = (const float*)d_in[3];
    const float* Wk    = (const float*)d_in[4];
    const float* bk    = (const float*)d_in[5];
    const float* w_att = (const float*)d_in[6];
    const float* b_att = (const float*)d_in[7];
    const float* Wt    = (const float*)d_in[8];
    const float* bt    = (const float*)d_in[9];
    float* out = (float*)d_out;

    float* Qb = (float*)d_ws;          // [L*D]
    float* Kb = Qb + L * D;            // [L*D] holds 2*(X@Wk+bk)
    float* Wb = Kb + L * D;            // [L*D] weighted

    // Q = X@Wq + bq ; K2 = 2*(X@Wk + bk)   (fused via blockIdx.z)
    gemm64<false><<<dim3(D / 64, L / 64, 2), 256, 0, stream>>>(
        X, Wq, bq, Qb, Wk, bk, Kb, nullptr, L, D, D, 1.f, 2.f);

    // scores -> softmax -> weighted
    attn_scores<<<dim3(L), 256, 0, stream>>>(Qb, Kb, X, mask, w_att, b_att, Wb);

    // out = weighted@Wt + bt + Q
    gemm64<true><<<dim3(D / 64, L / 64, 1), 256, 0, stream>>>(
        Wb, Wt, bt, out, Wt, bt, out, Qb, L, D, D, 1.f, 1.f);
}

// Round 3
// 268.396 us; speedup vs baseline: 2.5210x; 1.1941x over previous
//
#include <hip/hip_runtime.h>

#define L 512
#define D 768

// ---------------- GEMM: C = (A[MxK] @ W[KxN] + bias)*scale (+ optional addend)
// 64x64 tile, BK=16, 256 threads, 4x4 per thread. blockIdx.z selects weight set
// (fuses Q and K projections; K output pre-scaled by 2*log2(e) for the exp2 trick).
template<bool ADD>
__global__ __launch_bounds__(256) void gemm64(
    const float* __restrict__ A,
    const float* __restrict__ W0, const float* __restrict__ b0, float* __restrict__ C0,
    const float* __restrict__ W1, const float* __restrict__ b1, float* __restrict__ C1,
    const float* __restrict__ addend,
    int M, int N, int K, float sc0, float sc1)
{
    const float* Wm   = blockIdx.z ? W1 : W0;
    const float* bias = blockIdx.z ? b1 : b0;
    float*       C    = blockIdx.z ? C1 : C0;
    const float  scale = blockIdx.z ? sc1 : sc0;

    __shared__ float As[16][64];   // [kk][m]
    __shared__ float Bs[16][64];   // [kk][n]

    const int tid = threadIdx.x;
    const int tx = tid & 15, ty = tid >> 4;
    const int bx = blockIdx.x, by = blockIdx.y;

    float acc[4][4] = {};

    for (int k0 = 0; k0 < K; k0 += 16) {
        #pragma unroll
        for (int i = 0; i < 4; ++i) {
            int idx = tid + 256 * i;
            int m  = idx >> 4;
            int kk = idx & 15;
            As[kk][m] = A[(by * 64 + m) * K + k0 + kk];
        }
        #pragma unroll
        for (int i = 0; i < 4; ++i) {
            int idx = tid + 256 * i;
            int kk = idx >> 6;
            int n  = idx & 63;
            Bs[kk][n] = Wm[(k0 + kk) * N + bx * 64 + n];
        }
        __syncthreads();
        #pragma unroll
        for (int kk = 0; kk < 16; ++kk) {
            float4 a = *(const float4*)&As[kk][ty * 4];
            float4 b = *(const float4*)&Bs[kk][tx * 4];
            float av[4] = {a.x, a.y, a.z, a.w};
            float bv[4] = {b.x, b.y, b.z, b.w};
            #pragma unroll
            for (int i = 0; i < 4; ++i)
                #pragma unroll
                for (int j = 0; j < 4; ++j)
                    acc[i][j] = fmaf(av[i], bv[j], acc[i][j]);
        }
        __syncthreads();
    }

    #pragma unroll
    for (int i = 0; i < 4; ++i) {
        int row = by * 64 + ty * 4 + i;
        #pragma unroll
        for (int j = 0; j < 4; ++j) {
            int col = bx * 64 + tx * 4 + j;
            float v = (acc[i][j] + bias[col]) * scale;
            if (ADD) v += addend[row * N + col];
            C[row * N + col] = v;
        }
    }
}

// ---------------- scores + softmax + weighted = probs @ X ---------------------
// One block (512 threads = 8 waves) per query row q.
// tanh(x) = 1 - 2/(e^{2x}+1);  sum_d w*tanh(q+k) = Wsum - 2*sum_d w/(exp2(q'+k')+1)
// where q' = 2*log2e*q, k' = 2*log2e*k (k' pre-scaled in the K GEMM epilogue).
#define LOG2E2 2.88539008177792681f   // 2*log2(e)

__global__ __launch_bounds__(512) void attn_scores(
    const float* __restrict__ Qb, const float* __restrict__ Kb2,
    const float* __restrict__ X,  const float* __restrict__ mask,
    const float* __restrict__ w_att, const float* __restrict__ b_att,
    float* __restrict__ Wout)
{
    __shared__ float sc[L];
    __shared__ float red[8];

    const int q = blockIdx.x;
    const int tid = threadIdx.x;
    const int lane = tid & 63, wave = tid >> 6;

    // per-lane q' and w in registers (d = lane + 64*j)
    float qv[12], wv[12];
    float Wsum = 0.f;
    #pragma unroll
    for (int j = 0; j < 12; ++j) {
        int d = lane + 64 * j;
        qv[j] = LOG2E2 * Qb[q * D + d];
        wv[j] = w_att[d];
        Wsum += wv[j];
    }

    const float batt = b_att[0];
    // two independent k-rows per iteration for trans-pipe ILP
    for (int k = wave; k < L; k += 16) {
        const float* Kr0 = Kb2 + k * D;
        const float* Kr1 = Kb2 + (k + 8) * D;
        float acc0 = 0.f, acc1 = 0.f;
        #pragma unroll
        for (int j = 0; j < 12; ++j) {
            float t0 = exp2f(qv[j] + Kr0[lane + 64 * j]);
            float t1 = exp2f(qv[j] + Kr1[lane + 64 * j]);
            acc0 += __fdividef(wv[j], t0 + 1.f);
            acc1 += __fdividef(wv[j], t1 + 1.f);
        }
        float s0 = Wsum - 2.f * acc0;
        float s1 = Wsum - 2.f * acc1;
        #pragma unroll
        for (int off = 32; off; off >>= 1) {
            s0 += __shfl_xor(s0, off);
            s1 += __shfl_xor(s1, off);
        }
        if (lane == 0) {
            sc[k]     = s0 + batt + mask[k];
            sc[k + 8] = s1 + batt + mask[k + 8];
        }
    }
    __syncthreads();

    // softmax over 512 scores, one element per thread
    float v = sc[tid];
    float m = v;
    #pragma unroll
    for (int off = 32; off; off >>= 1) m = fmaxf(m, __shfl_xor(m, off));
    if (lane == 0) red[wave] = m;
    __syncthreads();
    float mm = red[0];
    #pragma unroll
    for (int i = 1; i < 8; ++i) mm = fmaxf(mm, red[i]);
    float e = __expf(v - mm);
    float s = e;
    #pragma unroll
    for (int off = 32; off; off >>= 1) s += __shfl_xor(s, off);
    __syncthreads();             // everyone done reading red[] for max
    if (lane == 0) red[wave] = s;
    __syncthreads();
    float tot = red[0];
    #pragma unroll
    for (int i = 1; i < 8; ++i) tot += red[i];
    sc[tid] = e * (1.f / tot);   // normalized prob
    __syncthreads();

    // weighted = p @ X ; 384 threads (6 waves) x float2 columns, coalesced
    if (tid < 384) {
        float2 a = make_float2(0.f, 0.f);
        #pragma unroll 4
        for (int k = 0; k < L; ++k) {
            float p = sc[k];
            float2 x = ((const float2*)(X + k * D))[tid];
            a.x = fmaf(p, x.x, a.x);
            a.y = fmaf(p, x.y, a.y);
        }
        ((float2*)(Wout + q * D))[tid] = a;
    }
}

extern "C" void kernel_launch(void* const* d_in, const int* in_sizes, int n_in,
                              void* d_out, int out_size, void* d_ws, size_t ws_size,
                              hipStream_t stream) {
    const float* X     = (const float*)d_in[0];
    const float* mask  = (const float*)d_in[1];
    const float* Wq    = (const float*)d_in[2];
    const float* bq    = (const float*)d_in[3];
    const float* Wk    = (const float*)d_in[4];
    const float* bk    = (const float*)d_in[5];
    const float* w_att = (const float*)d_in[6];
    const float* b_att = (const float*)d_in[7];
    const float* Wt    = (const float*)d_in[8];
    const float* bt    = (const float*)d_in[9];
    float* out = (float*)d_out;

    float* Qb = (float*)d_ws;          // [L*D]
    float* Kb = Qb + L * D;            // [L*D] holds 2*log2e*(X@Wk+bk)
    float* Wb = Kb + L * D;            // [L*D] weighted

    // Q = X@Wq + bq ; K' = 2*log2e*(X@Wk + bk)   (fused via blockIdx.z)
    gemm64<false><<<dim3(D / 64, L / 64, 2), 256, 0, stream>>>(
        X, Wq, bq, Qb, Wk, bk, Kb, nullptr, L, D, D, 1.f, LOG2E2);

    // scores -> softmax -> weighted
    attn_scores<<<dim3(L), 512, 0, stream>>>(Qb, Kb, X, mask, w_att, b_att, Wb);

    // out = weighted@Wt + bt + Q
    gemm64<true><<<dim3(D / 64, L / 64, 1), 256, 0, stream>>>(
        Wb, Wt, bt, out, Wt, bt, out, Qb, L, D, D, 1.f, 1.f);
}

// Round 4
// 164.738 us; speedup vs baseline: 4.1072x; 1.6292x over previous
//
#include <hip/hip_runtime.h>

#define L 512
#define D 768
#define LOG2E2 2.88539008177792681f   // 2*log2(e)

// ---------------- GEMM: C = (A[512xD] @ W[DxD] + bias)*scale (+ optional addend)
// 32x64 tile, BK=32, 256 threads, 2x4 per thread. blockIdx.z selects weight set.
template<bool ADD>
__global__ __launch_bounds__(256) void gemm32(
    const float* __restrict__ A,
    const float* __restrict__ W0, const float* __restrict__ b0, float* __restrict__ C0,
    const float* __restrict__ W1, const float* __restrict__ b1, float* __restrict__ C1,
    const float* __restrict__ addend, float sc0, float sc1)
{
    const float* Wm   = blockIdx.z ? W1 : W0;
    const float* bias = blockIdx.z ? b1 : b0;
    float*       C    = blockIdx.z ? C1 : C0;
    const float  scale = blockIdx.z ? sc1 : sc0;

    __shared__ float As[32][32];   // [kk][m], columns XOR-swizzled by (kk & 28)
    __shared__ float Bs[32][64];   // [kk][n]

    const int tid = threadIdx.x;
    const int tx = tid & 15;       // n/4
    const int ty = tid >> 4;       // m/2
    const int bx = blockIdx.x, by = blockIdx.y;

    const int am = tid >> 3;            // 0..31  A row
    const int ak = (tid & 7) * 4;       // 0..28  A k-offset (kc*4)
    const int bk = tid >> 4;            // 0..15  B k-row
    const int bn = (tid & 15) * 4;      // B col

    const float* Aptr = A + (by * 32 + am) * D + ak;
    const float* Bptr = Wm + bk * D + bx * 64 + bn;

    float acc[2][4] = {};

    for (int k0 = 0; k0 < D; k0 += 32) {
        float4 va  = *(const float4*)(Aptr + k0);
        float4 vb0 = *(const float4*)(Bptr + k0 * D);
        float4 vb1 = *(const float4*)(Bptr + (k0 + 16) * D);
        if (k0) __syncthreads();                 // protect prev-iter LDS reads
        // A: As[ak+i][am ^ ak]  (swizzle value = (kk>>2)<<2 = ak, same for i=0..3)
        {
            const int sw = am ^ ak;
            As[ak + 0][sw] = va.x;
            As[ak + 1][sw] = va.y;
            As[ak + 2][sw] = va.z;
            As[ak + 3][sw] = va.w;
        }
        *(float4*)&Bs[bk][bn]      = vb0;
        *(float4*)&Bs[bk + 16][bn] = vb1;
        __syncthreads();
        #pragma unroll
        for (int kk = 0; kk < 32; ++kk) {
            float2 a = *(const float2*)&As[kk][(ty * 2) ^ (kk & 28)];
            float4 b = *(const float4*)&Bs[kk][tx * 4];
            acc[0][0] = fmaf(a.x, b.x, acc[0][0]);
            acc[0][1] = fmaf(a.x, b.y, acc[0][1]);
            acc[0][2] = fmaf(a.x, b.z, acc[0][2]);
            acc[0][3] = fmaf(a.x, b.w, acc[0][3]);
            acc[1][0] = fmaf(a.y, b.x, acc[1][0]);
            acc[1][1] = fmaf(a.y, b.y, acc[1][1]);
            acc[1][2] = fmaf(a.y, b.z, acc[1][2]);
            acc[1][3] = fmaf(a.y, b.w, acc[1][3]);
        }
    }

    const int row = by * 32 + ty * 2;
    const int col = bx * 64 + tx * 4;
    float4 bv = *(const float4*)(bias + col);
    #pragma unroll
    for (int i = 0; i < 2; ++i) {
        float4 v;
        v.x = (acc[i][0] + bv.x) * scale;
        v.y = (acc[i][1] + bv.y) * scale;
        v.z = (acc[i][2] + bv.z) * scale;
        v.w = (acc[i][3] + bv.w) * scale;
        if (ADD) {
            float4 ad = *(const float4*)(addend + (row + i) * D + col);
            v.x += ad.x; v.y += ad.y; v.z += ad.z; v.w += ad.w;
        }
        *(float4*)(C + (row + i) * D + col) = v;
    }
}

// ---------------- scores + softmax + weighted, 2 query rows per block ---------
// 1024 threads = 16 waves. tanh identity: sum_d w*tanh = Wsum - 2*sum_d w/(exp2(q'+k')+1)
// with q' = LOG2E2*q, k' = LOG2E2*k (pre-scaled in K GEMM). Raw v_exp/v_rcp builtins.
__global__ __launch_bounds__(1024) void attn_scores(
    const float* __restrict__ Qb, const float* __restrict__ Kb2,
    const float* __restrict__ X,  const float* __restrict__ mask,
    const float* __restrict__ w_att, const float* __restrict__ b_att,
    float* __restrict__ Wout)
{
    __shared__ float sc[2][L];
    __shared__ float red1[16];
    __shared__ float red2[16];

    const int q0 = blockIdx.x * 2;
    const int tid = threadIdx.x;
    const int lane = tid & 63, wave = tid >> 6;

    // per-lane q' (two rows) and w in registers (d = lane + 64*j)
    float qv0[12], qv1[12], wv[12];
    float Wsum = 0.f;
    #pragma unroll
    for (int j = 0; j < 12; ++j) {
        int d = lane + 64 * j;
        qv0[j] = LOG2E2 * Qb[q0 * D + d];
        qv1[j] = LOG2E2 * Qb[(q0 + 1) * D + d];
        wv[j]  = w_att[d];
        Wsum  += wv[j];
    }

    const float batt = b_att[0];
    for (int k = wave; k < L; k += 16) {
        const float* Kr = Kb2 + k * D;
        float acc0 = 0.f, acc1 = 0.f;
        #pragma unroll
        for (int j = 0; j < 12; ++j) {
            float kv = Kr[lane + 64 * j];
            float t0 = __builtin_amdgcn_exp2f(qv0[j] + kv);
            float t1 = __builtin_amdgcn_exp2f(qv1[j] + kv);
            acc0 = fmaf(wv[j], __builtin_amdgcn_rcpf(t0 + 1.f), acc0);
            acc1 = fmaf(wv[j], __builtin_amdgcn_rcpf(t1 + 1.f), acc1);
        }
        float s0 = Wsum - 2.f * acc0;
        float s1 = Wsum - 2.f * acc1;
        #pragma unroll
        for (int off = 32; off; off >>= 1) {
            s0 += __shfl_xor(s0, off);
            s1 += __shfl_xor(s1, off);
        }
        if (lane == 0) {
            float mk = mask[k] + batt;
            sc[0][k] = s0 + mk;
            sc[1][k] = s1 + mk;
        }
    }
    __syncthreads();

    // softmax: thread owns (row = tid>>9, kk = tid&511)
    const int row = tid >> 9, kk = tid & 511;
    const int rbase = row * 8;
    float v = sc[row][kk];
    float m = v;
    #pragma unroll
    for (int off = 32; off; off >>= 1) m = fmaxf(m, __shfl_xor(m, off));
    if (lane == 0) red1[wave] = m;
    __syncthreads();
    float mm = red1[rbase];
    #pragma unroll
    for (int i = 1; i < 8; ++i) mm = fmaxf(mm, red1[rbase + i]);
    float e = __builtin_amdgcn_exp2f(1.44269504088896341f * (v - mm));
    float s = e;
    #pragma unroll
    for (int off = 32; off; off >>= 1) s += __shfl_xor(s, off);
    if (lane == 0) red2[wave] = s;
    __syncthreads();
    float tot = red2[rbase];
    #pragma unroll
    for (int i = 1; i < 8; ++i) tot += red2[rbase + i];
    sc[row][kk] = e * __builtin_amdgcn_rcpf(tot);
    __syncthreads();

    // weighted = p @ X, both rows share the X stream.
    // tid<768: wrow = tid&1, cp = tid>>1 (float2 column pair)
    if (tid < 768) {
        const int wrow = tid & 1;
        const int cp = tid >> 1;
        const float* scr = sc[wrow];
        float2 a = make_float2(0.f, 0.f);
        #pragma unroll 4
        for (int k = 0; k < L; ++k) {
            float p = scr[k];
            float2 x = ((const float2*)(X + k * D))[cp];
            a.x = fmaf(p, x.x, a.x);
            a.y = fmaf(p, x.y, a.y);
        }
        ((float2*)(Wout + (q0 + wrow) * D))[cp] = a;
    }
}

extern "C" void kernel_launch(void* const* d_in, const int* in_sizes, int n_in,
                              void* d_out, int out_size, void* d_ws, size_t ws_size,
                              hipStream_t stream) {
    const float* X     = (const float*)d_in[0];
    const float* mask  = (const float*)d_in[1];
    const float* Wq    = (const float*)d_in[2];
    const float* bq    = (const float*)d_in[3];
    const float* Wk    = (const float*)d_in[4];
    const float* bk    = (const float*)d_in[5];
    const float* w_att = (const float*)d_in[6];
    const float* b_att = (const float*)d_in[7];
    const float* Wt    = (const float*)d_in[8];
    const float* bt    = (const float*)d_in[9];
    float* out = (float*)d_out;

    float* Qb = (float*)d_ws;          // [L*D]
    float* Kb = Qb + L * D;            // [L*D] holds LOG2E2*(X@Wk+bk)
    float* Wb = Kb + L * D;            // [L*D] weighted

    // Q = X@Wq + bq ; K' = LOG2E2*(X@Wk + bk)   (fused via blockIdx.z)
    gemm32<false><<<dim3(D / 64, L / 32, 2), 256, 0, stream>>>(
        X, Wq, bq, Qb, Wk, bk, Kb, nullptr, 1.f, LOG2E2);

    // scores -> softmax -> weighted, 2 q-rows per block
    attn_scores<<<dim3(L / 2), 1024, 0, stream>>>(Qb, Kb, X, mask, w_att, b_att, Wb);

    // out = weighted@Wt + bt + Q
    gemm32<true><<<dim3(D / 64, L / 32, 1), 256, 0, stream>>>(
        Wb, Wt, bt, out, Wt, bt, out, Qb, 1.f, 1.f);
}

// Round 5
// 154.637 us; speedup vs baseline: 4.3755x; 1.0653x over previous
//
#include <hip/hip_runtime.h>

#define L 512
#define D 768
#define LOG2E  1.44269504088896341f
#define LOG2E2 2.88539008177792681f   // 2*log2(e)

// ---------------- GEMM: C = (A[512xD] @ W[DxD] + bias)*scale (+ optional addend)
// 32x64 tile, BK=32, 256 threads, 2x4 per thread. blockIdx.z selects weight set.
template<bool ADD>
__global__ __launch_bounds__(256) void gemm32(
    const float* __restrict__ A,
    const float* __restrict__ W0, const float* __restrict__ b0, float* __restrict__ C0,
    const float* __restrict__ W1, const float* __restrict__ b1, float* __restrict__ C1,
    const float* __restrict__ addend, float sc0, float sc1)
{
    const float* Wm   = blockIdx.z ? W1 : W0;
    const float* bias = blockIdx.z ? b1 : b0;
    float*       C    = blockIdx.z ? C1 : C0;
    const float  scale = blockIdx.z ? sc1 : sc0;

    __shared__ float As[32][32];   // [kk][m], columns XOR-swizzled by (kk & 28)
    __shared__ float Bs[32][64];   // [kk][n]

    const int tid = threadIdx.x;
    const int tx = tid & 15;
    const int ty = tid >> 4;
    const int bx = blockIdx.x, by = blockIdx.y;

    const int am = tid >> 3;
    const int ak = (tid & 7) * 4;
    const int bk = tid >> 4;
    const int bn = (tid & 15) * 4;

    const float* Aptr = A + (by * 32 + am) * D + ak;
    const float* Bptr = Wm + bk * D + bx * 64 + bn;

    float acc[2][4] = {};

    for (int k0 = 0; k0 < D; k0 += 32) {
        float4 va  = *(const float4*)(Aptr + k0);
        float4 vb0 = *(const float4*)(Bptr + k0 * D);
        float4 vb1 = *(const float4*)(Bptr + (k0 + 16) * D);
        if (k0) __syncthreads();
        {
            const int sw = am ^ ak;
            As[ak + 0][sw] = va.x;
            As[ak + 1][sw] = va.y;
            As[ak + 2][sw] = va.z;
            As[ak + 3][sw] = va.w;
        }
        *(float4*)&Bs[bk][bn]      = vb0;
        *(float4*)&Bs[bk + 16][bn] = vb1;
        __syncthreads();
        #pragma unroll
        for (int kk = 0; kk < 32; ++kk) {
            float2 a = *(const float2*)&As[kk][(ty * 2) ^ (kk & 28)];
            float4 b = *(const float4*)&Bs[kk][tx * 4];
            acc[0][0] = fmaf(a.x, b.x, acc[0][0]);
            acc[0][1] = fmaf(a.x, b.y, acc[0][1]);
            acc[0][2] = fmaf(a.x, b.z, acc[0][2]);
            acc[0][3] = fmaf(a.x, b.w, acc[0][3]);
            acc[1][0] = fmaf(a.y, b.x, acc[1][0]);
            acc[1][1] = fmaf(a.y, b.y, acc[1][1]);
            acc[1][2] = fmaf(a.y, b.z, acc[1][2]);
            acc[1][3] = fmaf(a.y, b.w, acc[1][3]);
        }
    }

    const int row = by * 32 + ty * 2;
    const int col = bx * 64 + tx * 4;
    float4 bv = *(const float4*)(bias + col);
    #pragma unroll
    for (int i = 0; i < 2; ++i) {
        float4 v;
        v.x = (acc[i][0] + bv.x) * scale;
        v.y = (acc[i][1] + bv.y) * scale;
        v.z = (acc[i][2] + bv.z) * scale;
        v.w = (acc[i][3] + bv.w) * scale;
        if (ADD) {
            float4 ad = *(const float4*)(addend + (row + i) * D + col);
            v.x += ad.x; v.y += ad.y; v.z += ad.z; v.w += ad.w;
        }
        *(float4*)(C + (row + i) * D + col) = v;
    }
}

// ---------------- raw scores, k-split for full occupancy ----------------------
// Grid (4 k-tiles, 512 q) x 256 threads (4 waves), no LDS, ~40 VGPR -> 100% occ cap.
// Each wave: 32 k-rows of its 128-k tile, processed in independent pairs.
// score = Wsum - 2*sum_d w/(exp2(q'+k')+1) + b_att + mask   (tanh identity)
__global__ __launch_bounds__(256) void score_k(
    const float* __restrict__ Qb, const float* __restrict__ Kb2,
    const float* __restrict__ mask, const float* __restrict__ w_att,
    const float* __restrict__ b_att, float* __restrict__ scores)
{
    const int kt = blockIdx.x;          // 0..3
    const int q  = blockIdx.y;          // 0..511
    const int tid = threadIdx.x;
    const int lane = tid & 63, wave = tid >> 6;

    float qv[12], wv[12];
    float Wsum = 0.f;
    #pragma unroll
    for (int j = 0; j < 12; ++j) {
        int d = lane + 64 * j;
        qv[j] = LOG2E2 * Qb[q * D + d];
        wv[j] = w_att[d];
        Wsum += wv[j];
    }
    const float batt = b_att[0];
    const int kbase = kt * 128 + wave;

    for (int i = 0; i < 32; i += 2) {
        const int ka = kbase + 4 * i;
        const int kb = ka + 4;
        const float* Ka = Kb2 + ka * D;
        const float* Kb = Kb2 + kb * D;
        float acc_a = 0.f, acc_b = 0.f;
        #pragma unroll
        for (int j = 0; j < 12; ++j) {
            const int d = lane + 64 * j;
            float ta = __builtin_amdgcn_exp2f(qv[j] + Ka[d]);
            float tb = __builtin_amdgcn_exp2f(qv[j] + Kb[d]);
            acc_a = fmaf(wv[j], __builtin_amdgcn_rcpf(ta + 1.f), acc_a);
            acc_b = fmaf(wv[j], __builtin_amdgcn_rcpf(tb + 1.f), acc_b);
        }
        float sa = Wsum - 2.f * acc_a;
        float sb = Wsum - 2.f * acc_b;
        #pragma unroll
        for (int off = 32; off; off >>= 1) {
            sa += __shfl_xor(sa, off);
            sb += __shfl_xor(sb, off);
        }
        if (lane == 0) {
            scores[q * L + ka] = sa + batt + mask[ka];
            scores[q * L + kb] = sb + batt + mask[kb];
        }
    }
}

// ---------------- softmax + weighted, 2 q-rows per block ----------------------
// 256 blocks x 512 threads (8 waves). One X float2 load feeds both rows (4 fma).
__global__ __launch_bounds__(512) void softmax_weighted(
    const float* __restrict__ scores, const float* __restrict__ X,
    float* __restrict__ Wout)
{
    __shared__ float p0[L], p1[L];
    __shared__ float redA[8], redB[8], redC[8], redD[8];

    const int q0 = blockIdx.x * 2;
    const int tid = threadIdx.x;
    const int lane = tid & 63, wave = tid >> 6;

    float v0 = scores[q0 * L + tid];
    float v1 = scores[(q0 + 1) * L + tid];

    float m0 = v0, m1 = v1;
    #pragma unroll
    for (int off = 32; off; off >>= 1) {
        m0 = fmaxf(m0, __shfl_xor(m0, off));
        m1 = fmaxf(m1, __shfl_xor(m1, off));
    }
    if (lane == 0) { redA[wave] = m0; redB[wave] = m1; }
    __syncthreads();
    float mm0 = redA[0], mm1 = redB[0];
    #pragma unroll
    for (int i = 1; i < 8; ++i) { mm0 = fmaxf(mm0, redA[i]); mm1 = fmaxf(mm1, redB[i]); }
    float e0 = __builtin_amdgcn_exp2f(LOG2E * (v0 - mm0));
    float e1 = __builtin_amdgcn_exp2f(LOG2E * (v1 - mm1));
    float s0 = e0, s1 = e1;
    #pragma unroll
    for (int off = 32; off; off >>= 1) {
        s0 += __shfl_xor(s0, off);
        s1 += __shfl_xor(s1, off);
    }
    if (lane == 0) { redC[wave] = s0; redD[wave] = s1; }
    __syncthreads();
    float t0 = redC[0], t1 = redD[0];
    #pragma unroll
    for (int i = 1; i < 8; ++i) { t0 += redC[i]; t1 += redD[i]; }
    p0[tid] = e0 * __builtin_amdgcn_rcpf(t0);
    p1[tid] = e1 * __builtin_amdgcn_rcpf(t1);
    __syncthreads();

    if (tid < 384) {
        float a0x = 0.f, a0y = 0.f, a1x = 0.f, a1y = 0.f;
        #pragma unroll 4
        for (int k = 0; k < L; ++k) {
            float2 x = ((const float2*)(X + k * D))[tid];
            float pa = p0[k], pb = p1[k];
            a0x = fmaf(pa, x.x, a0x); a0y = fmaf(pa, x.y, a0y);
            a1x = fmaf(pb, x.x, a1x); a1y = fmaf(pb, x.y, a1y);
        }
        ((float2*)(Wout + q0 * D))[tid]       = make_float2(a0x, a0y);
        ((float2*)(Wout + (q0 + 1) * D))[tid] = make_float2(a1x, a1y);
    }
}

extern "C" void kernel_launch(void* const* d_in, const int* in_sizes, int n_in,
                              void* d_out, int out_size, void* d_ws, size_t ws_size,
                              hipStream_t stream) {
    const float* X     = (const float*)d_in[0];
    const float* mask  = (const float*)d_in[1];
    const float* Wq    = (const float*)d_in[2];
    const float* bq    = (const float*)d_in[3];
    const float* Wk    = (const float*)d_in[4];
    const float* bk    = (const float*)d_in[5];
    const float* w_att = (const float*)d_in[6];
    const float* b_att = (const float*)d_in[7];
    const float* Wt    = (const float*)d_in[8];
    const float* bt    = (const float*)d_in[9];
    float* out = (float*)d_out;

    float* Qb = (float*)d_ws;          // [L*D]
    float* Kb = Qb + L * D;            // [L*D] holds LOG2E2*(X@Wk+bk)
    float* Wb = Kb + L * D;            // [L*D] weighted
    // scores scratch lives in d_out (1 MB of the 1.57 MB output buffer);
    // fully overwritten by the final GEMM afterwards -> deterministic.
    float* scores = out;               // [L*L]

    // Q = X@Wq + bq ; K' = LOG2E2*(X@Wk + bk)   (fused via blockIdx.z)
    gemm32<false><<<dim3(D / 64, L / 32, 2), 256, 0, stream>>>(
        X, Wq, bq, Qb, Wk, bk, Kb, nullptr, 1.f, LOG2E2);

    // raw scores, full-occupancy k-split
    score_k<<<dim3(4, L), 256, 0, stream>>>(Qb, Kb, mask, w_att, b_att, scores);

    // softmax + weighted, 2 q-rows per block
    softmax_weighted<<<dim3(L / 2), 512, 0, stream>>>(scores, X, Wb);

    // out = weighted@Wt + bt + Q
    gemm32<true><<<dim3(D / 64, L / 32, 1), 256, 0, stream>>>(
        Wb, Wt, bt, out, Wt, bt, out, Qb, 1.f, 1.f);
}

// Round 6
// 128.683 us; speedup vs baseline: 5.2580x; 1.2017x over previous
//
#include <hip/hip_runtime.h>

#define L 512
#define D 768
#define LOG2E  1.44269504088896341f
#define LOG2E2 2.88539008177792681f   // 2*log2(e)

// ---------------- GEMM: C = (A[512xD] @ W[DxD] + bias)*scale (+ addend) -------
// 32x64 tile, BK=32, 256 threads, 2x4 per thread. blockIdx.z selects weight set.
// EXP1: the z==1 output additionally gets exp2() applied (Ek precompute).
template<bool ADD, bool EXP1>
__global__ __launch_bounds__(256) void gemm32(
    const float* __restrict__ A,
    const float* __restrict__ W0, const float* __restrict__ b0, float* __restrict__ C0,
    const float* __restrict__ W1, const float* __restrict__ b1, float* __restrict__ C1,
    const float* __restrict__ addend, float sc0, float sc1)
{
    const float* Wm   = blockIdx.z ? W1 : W0;
    const float* bias = blockIdx.z ? b1 : b0;
    float*       C    = blockIdx.z ? C1 : C0;
    const float  scale = blockIdx.z ? sc1 : sc0;

    __shared__ float As[32][32];   // [kk][m], columns XOR-swizzled by (kk & 28)
    __shared__ float Bs[32][64];   // [kk][n]

    const int tid = threadIdx.x;
    const int tx = tid & 15;
    const int ty = tid >> 4;
    const int bx = blockIdx.x, by = blockIdx.y;

    const int am = tid >> 3;
    const int ak = (tid & 7) * 4;
    const int bk = tid >> 4;
    const int bn = (tid & 15) * 4;

    const float* Aptr = A + (by * 32 + am) * D + ak;
    const float* Bptr = Wm + bk * D + bx * 64 + bn;

    float acc[2][4] = {};

    for (int k0 = 0; k0 < D; k0 += 32) {
        float4 va  = *(const float4*)(Aptr + k0);
        float4 vb0 = *(const float4*)(Bptr + k0 * D);
        float4 vb1 = *(const float4*)(Bptr + (k0 + 16) * D);
        if (k0) __syncthreads();
        {
            const int sw = am ^ ak;
            As[ak + 0][sw] = va.x;
            As[ak + 1][sw] = va.y;
            As[ak + 2][sw] = va.z;
            As[ak + 3][sw] = va.w;
        }
        *(float4*)&Bs[bk][bn]      = vb0;
        *(float4*)&Bs[bk + 16][bn] = vb1;
        __syncthreads();
        #pragma unroll
        for (int kk = 0; kk < 32; ++kk) {
            float2 a = *(const float2*)&As[kk][(ty * 2) ^ (kk & 28)];
            float4 b = *(const float4*)&Bs[kk][tx * 4];
            acc[0][0] = fmaf(a.x, b.x, acc[0][0]);
            acc[0][1] = fmaf(a.x, b.y, acc[0][1]);
            acc[0][2] = fmaf(a.x, b.z, acc[0][2]);
            acc[0][3] = fmaf(a.x, b.w, acc[0][3]);
            acc[1][0] = fmaf(a.y, b.x, acc[1][0]);
            acc[1][1] = fmaf(a.y, b.y, acc[1][1]);
            acc[1][2] = fmaf(a.y, b.z, acc[1][2]);
            acc[1][3] = fmaf(a.y, b.w, acc[1][3]);
        }
    }

    const int row = by * 32 + ty * 2;
    const int col = bx * 64 + tx * 4;
    float4 bv = *(const float4*)(bias + col);
    const bool doexp = EXP1 && (blockIdx.z != 0);
    #pragma unroll
    for (int i = 0; i < 2; ++i) {
        float4 v;
        v.x = (acc[i][0] + bv.x) * scale;
        v.y = (acc[i][1] + bv.y) * scale;
        v.z = (acc[i][2] + bv.z) * scale;
        v.w = (acc[i][3] + bv.w) * scale;
        if (doexp) {
            v.x = __builtin_amdgcn_exp2f(v.x);
            v.y = __builtin_amdgcn_exp2f(v.y);
            v.z = __builtin_amdgcn_exp2f(v.z);
            v.w = __builtin_amdgcn_exp2f(v.w);
        }
        if (ADD) {
            float4 ad = *(const float4*)(addend + (row + i) * D + col);
            v.x += ad.x; v.y += ad.y; v.z += ad.z; v.w += ad.w;
        }
        *(float4*)(C + (row + i) * D + col) = v;
    }
}

// ---------------- raw scores, k-split for full occupancy ----------------------
// Grid (4 k-tiles, 512 q) x 256 threads (4 waves), no LDS.
// tanh identity + exp factorization: exp2(q'+k') = Eq*Ek with Ek precomputed.
// score = Wsum - 2*sum_d w * rcp(fma(Eq, Ek, 1)) + b_att + mask
__global__ __launch_bounds__(256) void score_k(
    const float* __restrict__ Qb, const float* __restrict__ Ek,
    const float* __restrict__ mask, const float* __restrict__ w_att,
    const float* __restrict__ b_att, float* __restrict__ scores)
{
    const int kt = blockIdx.x;          // 0..3
    const int q  = blockIdx.y;          // 0..511
    const int tid = threadIdx.x;
    const int lane = tid & 63, wave = tid >> 6;

    // lane owns d = 4*lane + 256*jj + i  (float4-friendly)
    float qe[3][4], wv[3][4];
    float Wsum = 0.f;
    #pragma unroll
    for (int jj = 0; jj < 3; ++jj) {
        float4 qv = *(const float4*)(Qb + q * D + 4 * lane + 256 * jj);
        float4 wq = *(const float4*)(w_att + 4 * lane + 256 * jj);
        qe[jj][0] = __builtin_amdgcn_exp2f(LOG2E2 * qv.x);
        qe[jj][1] = __builtin_amdgcn_exp2f(LOG2E2 * qv.y);
        qe[jj][2] = __builtin_amdgcn_exp2f(LOG2E2 * qv.z);
        qe[jj][3] = __builtin_amdgcn_exp2f(LOG2E2 * qv.w);
        wv[jj][0] = wq.x; wv[jj][1] = wq.y; wv[jj][2] = wq.z; wv[jj][3] = wq.w;
        Wsum += wq.x + wq.y + wq.z + wq.w;
    }
    const float batt = b_att[0];
    const int kbase = kt * 128 + wave;

    for (int i = 0; i < 32; i += 2) {
        const int ka = kbase + 4 * i;
        const int kb = ka + 4;
        const float4* Ka4 = (const float4*)(Ek + ka * D) + lane;
        const float4* Kb4 = (const float4*)(Ek + kb * D) + lane;
        float acc_a = 0.f, acc_b = 0.f;
        #pragma unroll
        for (int jj = 0; jj < 3; ++jj) {
            float4 a = Ka4[64 * jj];
            float4 b = Kb4[64 * jj];
            acc_a = fmaf(wv[jj][0], __builtin_amdgcn_rcpf(fmaf(qe[jj][0], a.x, 1.f)), acc_a);
            acc_a = fmaf(wv[jj][1], __builtin_amdgcn_rcpf(fmaf(qe[jj][1], a.y, 1.f)), acc_a);
            acc_a = fmaf(wv[jj][2], __builtin_amdgcn_rcpf(fmaf(qe[jj][2], a.z, 1.f)), acc_a);
            acc_a = fmaf(wv[jj][3], __builtin_amdgcn_rcpf(fmaf(qe[jj][3], a.w, 1.f)), acc_a);
            acc_b = fmaf(wv[jj][0], __builtin_amdgcn_rcpf(fmaf(qe[jj][0], b.x, 1.f)), acc_b);
            acc_b = fmaf(wv[jj][1], __builtin_amdgcn_rcpf(fmaf(qe[jj][1], b.y, 1.f)), acc_b);
            acc_b = fmaf(wv[jj][2], __builtin_amdgcn_rcpf(fmaf(qe[jj][2], b.z, 1.f)), acc_b);
            acc_b = fmaf(wv[jj][3], __builtin_amdgcn_rcpf(fmaf(qe[jj][3], b.w, 1.f)), acc_b);
        }
        float sa = Wsum - 2.f * acc_a;
        float sb = Wsum - 2.f * acc_b;
        #pragma unroll
        for (int off = 32; off; off >>= 1) {
            sa += __shfl_xor(sa, off);
            sb += __shfl_xor(sb, off);
        }
        if (lane == 0) {
            scores[q * L + ka] = sa + batt + mask[ka];
            scores[q * L + kb] = sb + batt + mask[kb];
        }
    }
}

// ---------------- softmax + weighted, 2 q-rows per block ----------------------
// 256 blocks x 512 threads. Probs packed as float2 (one LDS b64 broadcast serves
// both rows); weighted loop split into two independent k-streams for 8 loads
// in flight per thread.
__global__ __launch_bounds__(512) void softmax_weighted(
    const float* __restrict__ scores, const float* __restrict__ X,
    float* __restrict__ Wout)
{
    __shared__ float2 pp[L];
    __shared__ float redA[8], redB[8], redC[8], redD[8];

    const int q0 = blockIdx.x * 2;
    const int tid = threadIdx.x;
    const int lane = tid & 63, wave = tid >> 6;

    float v0 = scores[q0 * L + tid];
    float v1 = scores[(q0 + 1) * L + tid];

    float m0 = v0, m1 = v1;
    #pragma unroll
    for (int off = 32; off; off >>= 1) {
        m0 = fmaxf(m0, __shfl_xor(m0, off));
        m1 = fmaxf(m1, __shfl_xor(m1, off));
    }
    if (lane == 0) { redA[wave] = m0; redB[wave] = m1; }
    __syncthreads();
    float mm0 = redA[0], mm1 = redB[0];
    #pragma unroll
    for (int i = 1; i < 8; ++i) { mm0 = fmaxf(mm0, redA[i]); mm1 = fmaxf(mm1, redB[i]); }
    float e0 = __builtin_amdgcn_exp2f(LOG2E * (v0 - mm0));
    float e1 = __builtin_amdgcn_exp2f(LOG2E * (v1 - mm1));
    float s0 = e0, s1 = e1;
    #pragma unroll
    for (int off = 32; off; off >>= 1) {
        s0 += __shfl_xor(s0, off);
        s1 += __shfl_xor(s1, off);
    }
    if (lane == 0) { redC[wave] = s0; redD[wave] = s1; }
    __syncthreads();
    float t0 = redC[0], t1 = redD[0];
    #pragma unroll
    for (int i = 1; i < 8; ++i) { t0 += redC[i]; t1 += redD[i]; }
    pp[tid] = make_float2(e0 * __builtin_amdgcn_rcpf(t0),
                          e1 * __builtin_amdgcn_rcpf(t1));
    __syncthreads();

    if (tid < 384) {
        const float2* X2 = (const float2*)X;   // row stride D/2 = 384
        float a0x = 0.f, a0y = 0.f, a1x = 0.f, a1y = 0.f;
        float b0x = 0.f, b0y = 0.f, b1x = 0.f, b1y = 0.f;
        #pragma unroll 4
        for (int k = 0; k < 256; ++k) {
            float2 p  = pp[k];
            float2 x  = X2[k * 384 + tid];
            a0x = fmaf(p.x, x.x, a0x);  a0y = fmaf(p.x, x.y, a0y);
            a1x = fmaf(p.y, x.x, a1x);  a1y = fmaf(p.y, x.y, a1y);
            float2 p2 = pp[k + 256];
            float2 x2 = X2[(k + 256) * 384 + tid];
            b0x = fmaf(p2.x, x2.x, b0x);  b0y = fmaf(p2.x, x2.y, b0y);
            b1x = fmaf(p2.y, x2.x, b1x);  b1y = fmaf(p2.y, x2.y, b1y);
        }
        ((float2*)(Wout + q0 * D))[tid]       = make_float2(a0x + b0x, a0y + b0y);
        ((float2*)(Wout + (q0 + 1) * D))[tid] = make_float2(a1x + b1x, a1y + b1y);
    }
}

extern "C" void kernel_launch(void* const* d_in, const int* in_sizes, int n_in,
                              void* d_out, int out_size, void* d_ws, size_t ws_size,
                              hipStream_t stream) {
    const float* X     = (const float*)d_in[0];
    const float* mask  = (const float*)d_in[1];
    const float* Wq    = (const float*)d_in[2];
    const float* bq    = (const float*)d_in[3];
    const float* Wk    = (const float*)d_in[4];
    const float* bk    = (const float*)d_in[5];
    const float* w_att = (const float*)d_in[6];
    const float* b_att = (const float*)d_in[7];
    const float* Wt    = (const float*)d_in[8];
    const float* bt    = (const float*)d_in[9];
    float* out = (float*)d_out;

    float* Qb = (float*)d_ws;          // [L*D] raw Q (also final addend)
    float* Ek = Qb + L * D;            // [L*D] exp2(LOG2E2*(X@Wk+bk))
    float* Wb = Ek + L * D;            // [L*D] weighted
    // scores scratch lives in d_out (1 MB of the 1.57 MB output buffer);
    // fully overwritten by the final GEMM afterwards -> deterministic.
    float* scores = out;               // [L*L]

    // Q = X@Wq + bq ; Ek = exp2(LOG2E2*(X@Wk + bk))   (fused via blockIdx.z)
    gemm32<false, true><<<dim3(D / 64, L / 32, 2), 256, 0, stream>>>(
        X, Wq, bq, Qb, Wk, bk, Ek, nullptr, 1.f, LOG2E2);

    // raw scores, full-occupancy k-split
    score_k<<<dim3(4, L), 256, 0, stream>>>(Qb, Ek, mask, w_att, b_att, scores);

    // softmax + weighted, 2 q-rows per block
    softmax_weighted<<<dim3(L / 2), 512, 0, stream>>>(scores, X, Wb);

    // out = weighted@Wt + bt + Q
    gemm32<true, false><<<dim3(D / 64, L / 32, 1), 256, 0, stream>>>(
        Wb, Wt, bt, out, Wt, bt, out, Qb, 1.f, 1.f);
}

// Round 7
// 77.093 us; speedup vs baseline: 8.7767x; 1.6692x over previous
//
#include <hip/hip_runtime.h>

#define L 512
#define D 768
#define LOG2E  1.44269504088896341f
#define LOG2E2 2.88539008177792681f   // 2*log2(e)

typedef __attribute__((ext_vector_type(8))) short bf16x8;
typedef __attribute__((ext_vector_type(4))) float f32x4;

__device__ __forceinline__ ushort f2bf(float f) {
    unsigned u = __builtin_bit_cast(unsigned, f);
    u += 0x7FFFu + ((u >> 16) & 1u);          // RNE
    return (ushort)(u >> 16);
}

// ---------------- prep: cast X->bf16 and build transposed bf16 copies ---------
// z: 0 = X (512x768; also writes straight cast), 1 = Wq, 2 = Wk, 3 = Wt (768x768)
__global__ __launch_bounds__(256) void transpose_cast(
    const float* __restrict__ X,  const float* __restrict__ Wq,
    const float* __restrict__ Wk, const float* __restrict__ Wt,
    ushort* __restrict__ Xbf, ushort* __restrict__ XbfT,
    ushort* __restrict__ WqT, ushort* __restrict__ WkT, ushort* __restrict__ WtT)
{
    __shared__ float tile[64][65];
    const int z = blockIdx.z;
    const float* src = z == 0 ? X : z == 1 ? Wq : z == 2 ? Wk : Wt;
    ushort* dstT     = z == 0 ? XbfT : z == 1 ? WqT : z == 2 ? WkT : WtT;
    const int R = (z == 0) ? L : D;
    const int r0 = blockIdx.y * 64, c0 = blockIdx.x * 64;
    if (r0 >= R) return;
    const int t = threadIdx.x;
    const int tr = t >> 4;           // 0..15
    const int tc = (t & 15) * 4;     // 0..60
    #pragma unroll
    for (int p = 0; p < 4; ++p) {
        int r = tr + p * 16;
        float4 v = *(const float4*)&src[(r0 + r) * D + c0 + tc];
        tile[r][tc + 0] = v.x; tile[r][tc + 1] = v.y;
        tile[r][tc + 2] = v.z; tile[r][tc + 3] = v.w;
        if (z == 0) {
            ushort4 b;
            b.x = f2bf(v.x); b.y = f2bf(v.y); b.z = f2bf(v.z); b.w = f2bf(v.w);
            *(ushort4*)&Xbf[(r0 + r) * D + c0 + tc] = b;
        }
    }
    __syncthreads();
    #pragma unroll
    for (int p = 0; p < 4; ++p) {
        int c = tr + p * 16;
        ushort4 b;
        b.x = f2bf(tile[tc + 0][c]);
        b.y = f2bf(tile[tc + 1][c]);
        b.z = f2bf(tile[tc + 2][c]);
        b.w = f2bf(tile[tc + 3][c]);
        *(ushort4*)&dstT[(c0 + c) * R + r0 + tc] = b;
    }
}

// ---------------- bf16 MFMA GEMM: C = A[512xK] @ Bt^T[KxN] (+bias)(+exp)(+add)
// 64x64 tile, 256 threads (4 waves, each a 32x32 quadrant = 2x2 16x16 frags),
// BK=64. A row-major bf16; Bt is B transposed [N][K] bf16 -> both staged with
// contiguous k, fragments read as one b128. N fixed at 768.
template<bool ZSEL, bool EXPZ, bool OUTBF, bool HASBIAS, bool ADDQ>
__global__ __launch_bounds__(256) void gemm_mfma(
    const ushort* __restrict__ A,
    const ushort* __restrict__ Bt0, const ushort* __restrict__ Bt1,
    const float* __restrict__ bias0, const float* __restrict__ bias1,
    float* __restrict__ Cf0, float* __restrict__ Cf1,
    ushort* __restrict__ Cb,
    const float* __restrict__ addend, int K)
{
    const int N = D;
    const int bz = ZSEL ? blockIdx.z : 0;
    const ushort* Bt  = (ZSEL && bz) ? Bt1 : Bt0;
    const float*  bias = (ZSEL && bz) ? bias1 : bias0;
    float*        Cf  = (ZSEL && bz) ? Cf1 : Cf0;

    __shared__ ushort As[64][72];   // +8 pad: row stride 144B -> ~2-way banks
    __shared__ ushort Bs[64][72];

    const int m0 = blockIdx.y * 64;
    const int n0 = blockIdx.x * 64;
    const int t = threadIdx.x;
    const int l = t & 63, w = t >> 6;
    const int wr = w >> 1, wc = w & 1;
    const int frow = l & 15;
    const int kg = (l >> 4) * 8;

    const int srow = t >> 3;         // 0..31
    const int sk   = (t & 7) * 8;    // 0..56

    f32x4 acc[2][2] = {};

    for (int k0 = 0; k0 < K; k0 += 64) {
        uint4 a0 = *(const uint4*)&A [(m0 + srow)      * K + k0 + sk];
        uint4 a1 = *(const uint4*)&A [(m0 + srow + 32) * K + k0 + sk];
        uint4 b0 = *(const uint4*)&Bt[(n0 + srow)      * K + k0 + sk];
        uint4 b1 = *(const uint4*)&Bt[(n0 + srow + 32) * K + k0 + sk];
        if (k0) __syncthreads();
        *(uint4*)&As[srow][sk]      = a0;
        *(uint4*)&As[srow + 32][sk] = a1;
        *(uint4*)&Bs[srow][sk]      = b0;
        *(uint4*)&Bs[srow + 32][sk] = b1;
        __syncthreads();

        bf16x8 af[2][2], bfr[2][2];
        #pragma unroll
        for (int fr = 0; fr < 2; ++fr)
            #pragma unroll
            for (int kk = 0; kk < 2; ++kk) {
                af[fr][kk]  = *(const bf16x8*)&As[32 * wr + 16 * fr + frow][32 * kk + kg];
                bfr[fr][kk] = *(const bf16x8*)&Bs[32 * wc + 16 * fr + frow][32 * kk + kg];
            }
        #pragma unroll
        for (int fr = 0; fr < 2; ++fr)
            #pragma unroll
            for (int fc = 0; fc < 2; ++fc) {
                acc[fr][fc] = __builtin_amdgcn_mfma_f32_16x16x32_bf16(
                    af[fr][0], bfr[fc][0], acc[fr][fc], 0, 0, 0);
                acc[fr][fc] = __builtin_amdgcn_mfma_f32_16x16x32_bf16(
                    af[fr][1], bfr[fc][1], acc[fr][fc], 0, 0, 0);
            }
    }

    const int rg = (l >> 4) * 4;
    #pragma unroll
    for (int fr = 0; fr < 2; ++fr)
        #pragma unroll
        for (int fc = 0; fc < 2; ++fc) {
            const int col = n0 + 32 * wc + 16 * fc + frow;
            const float bv = HASBIAS ? bias[col] : 0.f;
            #pragma unroll
            for (int i = 0; i < 4; ++i) {
                const int row = m0 + 32 * wr + 16 * fr + rg + i;
                float v = acc[fr][fc][i] + bv;
                if (EXPZ && bz) v = __builtin_amdgcn_exp2f(LOG2E2 * v);
                if (ADDQ) v += addend[row * N + col];
                if (OUTBF) Cb[row * N + col] = f2bf(v);
                else       Cf[row * N + col] = v;
            }
        }
}

// ---------------- raw scores, k-split for full occupancy (unchanged) ----------
__global__ __launch_bounds__(256) void score_k(
    const float* __restrict__ Qb, const float* __restrict__ Ek,
    const float* __restrict__ mask, const float* __restrict__ w_att,
    const float* __restrict__ b_att, float* __restrict__ scores)
{
    const int kt = blockIdx.x;
    const int q  = blockIdx.y;
    const int tid = threadIdx.x;
    const int lane = tid & 63, wave = tid >> 6;

    float qe[3][4], wv[3][4];
    float Wsum = 0.f;
    #pragma unroll
    for (int jj = 0; jj < 3; ++jj) {
        float4 qv = *(const float4*)(Qb + q * D + 4 * lane + 256 * jj);
        float4 wq = *(const float4*)(w_att + 4 * lane + 256 * jj);
        qe[jj][0] = __builtin_amdgcn_exp2f(LOG2E2 * qv.x);
        qe[jj][1] = __builtin_amdgcn_exp2f(LOG2E2 * qv.y);
        qe[jj][2] = __builtin_amdgcn_exp2f(LOG2E2 * qv.z);
        qe[jj][3] = __builtin_amdgcn_exp2f(LOG2E2 * qv.w);
        wv[jj][0] = wq.x; wv[jj][1] = wq.y; wv[jj][2] = wq.z; wv[jj][3] = wq.w;
        Wsum += wq.x + wq.y + wq.z + wq.w;
    }
    const float batt = b_att[0];
    const int kbase = kt * 128 + wave;

    for (int i = 0; i < 32; i += 2) {
        const int ka = kbase + 4 * i;
        const int kb = ka + 4;
        const float4* Ka4 = (const float4*)(Ek + ka * D) + lane;
        const float4* Kb4 = (const float4*)(Ek + kb * D) + lane;
        float acc_a = 0.f, acc_b = 0.f;
        #pragma unroll
        for (int jj = 0; jj < 3; ++jj) {
            float4 a = Ka4[64 * jj];
            float4 b = Kb4[64 * jj];
            acc_a = fmaf(wv[jj][0], __builtin_amdgcn_rcpf(fmaf(qe[jj][0], a.x, 1.f)), acc_a);
            acc_a = fmaf(wv[jj][1], __builtin_amdgcn_rcpf(fmaf(qe[jj][1], a.y, 1.f)), acc_a);
            acc_a = fmaf(wv[jj][2], __builtin_amdgcn_rcpf(fmaf(qe[jj][2], a.z, 1.f)), acc_a);
            acc_a = fmaf(wv[jj][3], __builtin_amdgcn_rcpf(fmaf(qe[jj][3], a.w, 1.f)), acc_a);
            acc_b = fmaf(wv[jj][0], __builtin_amdgcn_rcpf(fmaf(qe[jj][0], b.x, 1.f)), acc_b);
            acc_b = fmaf(wv[jj][1], __builtin_amdgcn_rcpf(fmaf(qe[jj][1], b.y, 1.f)), acc_b);
            acc_b = fmaf(wv[jj][2], __builtin_amdgcn_rcpf(fmaf(qe[jj][2], b.z, 1.f)), acc_b);
            acc_b = fmaf(wv[jj][3], __builtin_amdgcn_rcpf(fmaf(qe[jj][3], b.w, 1.f)), acc_b);
        }
        float sa = Wsum - 2.f * acc_a;
        float sb = Wsum - 2.f * acc_b;
        #pragma unroll
        for (int off = 32; off; off >>= 1) {
            sa += __shfl_xor(sa, off);
            sb += __shfl_xor(sb, off);
        }
        if (lane == 0) {
            scores[q * L + ka] = sa + batt + mask[ka];
            scores[q * L + kb] = sb + batt + mask[kb];
        }
    }
}

// ---------------- softmax -> bf16 probs, 2 q-rows per block ------------------
__global__ __launch_bounds__(512) void softmax_probs(
    const float* __restrict__ scores, ushort* __restrict__ Pbf)
{
    __shared__ float redA[8], redB[8], redC[8], redD[8];
    const int q0 = blockIdx.x * 2;
    const int tid = threadIdx.x;
    const int lane = tid & 63, wave = tid >> 6;

    float v0 = scores[q0 * L + tid];
    float v1 = scores[(q0 + 1) * L + tid];

    float m0 = v0, m1 = v1;
    #pragma unroll
    for (int off = 32; off; off >>= 1) {
        m0 = fmaxf(m0, __shfl_xor(m0, off));
        m1 = fmaxf(m1, __shfl_xor(m1, off));
    }
    if (lane == 0) { redA[wave] = m0; redB[wave] = m1; }
    __syncthreads();
    float mm0 = redA[0], mm1 = redB[0];
    #pragma unroll
    for (int i = 1; i < 8; ++i) { mm0 = fmaxf(mm0, redA[i]); mm1 = fmaxf(mm1, redB[i]); }
    float e0 = __builtin_amdgcn_exp2f(LOG2E * (v0 - mm0));
    float e1 = __builtin_amdgcn_exp2f(LOG2E * (v1 - mm1));
    float s0 = e0, s1 = e1;
    #pragma unroll
    for (int off = 32; off; off >>= 1) {
        s0 += __shfl_xor(s0, off);
        s1 += __shfl_xor(s1, off);
    }
    if (lane == 0) { redC[wave] = s0; redD[wave] = s1; }
    __syncthreads();
    float t0 = redC[0], t1 = redD[0];
    #pragma unroll
    for (int i = 1; i < 8; ++i) { t0 += redC[i]; t1 += redD[i]; }
    Pbf[q0 * L + tid]       = f2bf(e0 * __builtin_amdgcn_rcpf(t0));
    Pbf[(q0 + 1) * L + tid] = f2bf(e1 * __builtin_amdgcn_rcpf(t1));
}

extern "C" void kernel_launch(void* const* d_in, const int* in_sizes, int n_in,
                              void* d_out, int out_size, void* d_ws, size_t ws_size,
                              hipStream_t stream) {
    const float* X     = (const float*)d_in[0];
    const float* mask  = (const float*)d_in[1];
    const float* Wq    = (const float*)d_in[2];
    const float* bq    = (const float*)d_in[3];
    const float* Wk    = (const float*)d_in[4];
    const float* bk    = (const float*)d_in[5];
    const float* w_att = (const float*)d_in[6];
    const float* b_att = (const float*)d_in[7];
    const float* Wt    = (const float*)d_in[8];
    const float* bt    = (const float*)d_in[9];
    float* out = (float*)d_out;

    const int LD = L * D, DD = D * D, LL = L * L;
    float*  Qb   = (float*)d_ws;          // [L*D] fp32 Q (score input + final addend)
    float*  Ek   = Qb + LD;               // [L*D] fp32 exp2(LOG2E2*(X@Wk+bk))
    ushort* Xbf  = (ushort*)(Ek + LD);    // [L*D] bf16 X
    ushort* XbfT = Xbf + LD;              // [D][L] bf16 X^T
    ushort* WqT  = XbfT + LD;             // [D][D]
    ushort* WkT  = WqT + DD;
    ushort* WtT  = WkT + DD;
    ushort* Pbf  = WtT + DD;              // [L][L] bf16 probs
    ushort* Wbf  = Pbf + LL;              // [L][D] bf16 weighted
    // scores scratch in d_out (1 MB of 1.57 MB), overwritten by final GEMM.
    float* scores = out;                  // [L*L]

    // prep: bf16 casts + transposes
    transpose_cast<<<dim3(D / 64, D / 64, 4), 256, 0, stream>>>(
        X, Wq, Wk, Wt, Xbf, XbfT, WqT, WkT, WtT);

    // Q = X@Wq + bq (fp32) ; Ek = exp2(LOG2E2*(X@Wk + bk)) (fp32), fused via z
    gemm_mfma<true, true, false, true, false><<<dim3(D / 64, L / 64, 2), 256, 0, stream>>>(
        Xbf, WqT, WkT, bq, bk, Qb, Ek, nullptr, nullptr, D);

    // raw scores
    score_k<<<dim3(4, L), 256, 0, stream>>>(Qb, Ek, mask, w_att, b_att, scores);

    // softmax -> bf16 probs
    softmax_probs<<<dim3(L / 2), 512, 0, stream>>>(scores, Pbf);

    // weighted = probs @ X  (bf16 out)
    gemm_mfma<false, false, true, false, false><<<dim3(D / 64, L / 64, 1), 256, 0, stream>>>(
        Pbf, XbfT, nullptr, nullptr, nullptr, nullptr, nullptr, Wbf, nullptr, L);

    // out = weighted@Wt + bt + Q  (fp32)
    gemm_mfma<false, false, false, true, true><<<dim3(D / 64, L / 64, 1), 256, 0, stream>>>(
        Wbf, WtT, nullptr, bt, nullptr, out, nullptr, nullptr, Qb, D);
}

// Round 8
// 70.932 us; speedup vs baseline: 9.5390x; 1.0869x over previous
//
#include <hip/hip_runtime.h>

#define L 512
#define D 768
#define LOG2E  1.44269504088896341f
#define LOG2E2 2.88539008177792681f   // 2*log2(e)

typedef __attribute__((ext_vector_type(8))) short bf16x8;
typedef __attribute__((ext_vector_type(4))) float f32x4;

__device__ __forceinline__ ushort f2bf(float f) {
    unsigned u = __builtin_bit_cast(unsigned, f);
    u += 0x7FFFu + ((u >> 16) & 1u);          // RNE
    return (ushort)(u >> 16);
}

// ---------------- prep: cast X->bf16 and build transposed bf16 copies ---------
// z: 0 = X (512x768; also writes straight cast), 1 = Wq, 2 = Wk, 3 = Wt (768x768)
__global__ __launch_bounds__(256) void transpose_cast(
    const float* __restrict__ X,  const float* __restrict__ Wq,
    const float* __restrict__ Wk, const float* __restrict__ Wt,
    ushort* __restrict__ Xbf, ushort* __restrict__ XbfT,
    ushort* __restrict__ WqT, ushort* __restrict__ WkT, ushort* __restrict__ WtT)
{
    __shared__ float tile[64][65];
    const int z = blockIdx.z;
    const float* src = z == 0 ? X : z == 1 ? Wq : z == 2 ? Wk : Wt;
    ushort* dstT     = z == 0 ? XbfT : z == 1 ? WqT : z == 2 ? WkT : WtT;
    const int R = (z == 0) ? L : D;
    const int r0 = blockIdx.y * 64, c0 = blockIdx.x * 64;
    if (r0 >= R) return;
    const int t = threadIdx.x;
    const int tr = t >> 4;           // 0..15
    const int tc = (t & 15) * 4;     // 0..60
    #pragma unroll
    for (int p = 0; p < 4; ++p) {
        int r = tr + p * 16;
        float4 v = *(const float4*)&src[(r0 + r) * D + c0 + tc];
        tile[r][tc + 0] = v.x; tile[r][tc + 1] = v.y;
        tile[r][tc + 2] = v.z; tile[r][tc + 3] = v.w;
        if (z == 0) {
            ushort4 b;
            b.x = f2bf(v.x); b.y = f2bf(v.y); b.z = f2bf(v.z); b.w = f2bf(v.w);
            *(ushort4*)&Xbf[(r0 + r) * D + c0 + tc] = b;
        }
    }
    __syncthreads();
    #pragma unroll
    for (int p = 0; p < 4; ++p) {
        int c = tr + p * 16;
        ushort4 b;
        b.x = f2bf(tile[tc + 0][c]);
        b.y = f2bf(tile[tc + 1][c]);
        b.z = f2bf(tile[tc + 2][c]);
        b.w = f2bf(tile[tc + 3][c]);
        *(ushort4*)&dstT[(c0 + c) * R + r0 + tc] = b;
    }
}

// ---------------- bf16 MFMA GEMM: C = A[512xK] @ Bt^T[KxN] (+bias)(+exp)(+add)
// 32x64 tile, 256 threads = 4 waves in 2x2; each wave a 16x32 quadrant
// (1x2 16x16 frags), BK=64. A row-major bf16; Bt transposed [N][K] bf16.
template<bool ZSEL, bool EXPZ, bool OUTBF, bool HASBIAS, bool ADDQ>
__global__ __launch_bounds__(256) void gemm_mfma(
    const ushort* __restrict__ A,
    const ushort* __restrict__ Bt0, const ushort* __restrict__ Bt1,
    const float* __restrict__ bias0, const float* __restrict__ bias1,
    float* __restrict__ Cf0, float* __restrict__ Cf1,
    ushort* __restrict__ Cb,
    const float* __restrict__ addend, int K)
{
    const int N = D;
    const int bz = ZSEL ? blockIdx.z : 0;
    const ushort* Bt   = (ZSEL && bz) ? Bt1 : Bt0;
    const float*  bias = (ZSEL && bz) ? bias1 : bias0;
    float*        Cf   = (ZSEL && bz) ? Cf1 : Cf0;

    __shared__ ushort As[32][72];   // +8 pad
    __shared__ ushort Bs[64][72];

    const int m0 = blockIdx.y * 32;
    const int n0 = blockIdx.x * 64;
    const int t = threadIdx.x;
    const int l = t & 63, w = t >> 6;
    const int wr = w >> 1, wc = w & 1;
    const int frow = l & 15;
    const int kg = (l >> 4) * 8;

    const int srow = t >> 3;         // 0..31
    const int sk   = (t & 7) * 8;    // 0..56

    f32x4 acc[2] = {};

    for (int k0 = 0; k0 < K; k0 += 64) {
        uint4 a0 = *(const uint4*)&A [(m0 + srow)      * K + k0 + sk];
        uint4 b0 = *(const uint4*)&Bt[(n0 + srow)      * K + k0 + sk];
        uint4 b1 = *(const uint4*)&Bt[(n0 + srow + 32) * K + k0 + sk];
        if (k0) __syncthreads();
        *(uint4*)&As[srow][sk]      = a0;
        *(uint4*)&Bs[srow][sk]      = b0;
        *(uint4*)&Bs[srow + 32][sk] = b1;
        __syncthreads();

        bf16x8 af[2], bfr[2][2];
        #pragma unroll
        for (int kk = 0; kk < 2; ++kk) {
            af[kk] = *(const bf16x8*)&As[16 * wr + frow][32 * kk + kg];
            #pragma unroll
            for (int fc = 0; fc < 2; ++fc)
                bfr[fc][kk] = *(const bf16x8*)&Bs[32 * wc + 16 * fc + frow][32 * kk + kg];
        }
        #pragma unroll
        for (int fc = 0; fc < 2; ++fc) {
            acc[fc] = __builtin_amdgcn_mfma_f32_16x16x32_bf16(af[0], bfr[fc][0], acc[fc], 0, 0, 0);
            acc[fc] = __builtin_amdgcn_mfma_f32_16x16x32_bf16(af[1], bfr[fc][1], acc[fc], 0, 0, 0);
        }
    }

    const int rg = (l >> 4) * 4;
    #pragma unroll
    for (int fc = 0; fc < 2; ++fc) {
        const int col = n0 + 32 * wc + 16 * fc + frow;
        const float bv = HASBIAS ? bias[col] : 0.f;
        #pragma unroll
        for (int i = 0; i < 4; ++i) {
            const int row = m0 + 16 * wr + rg + i;
            float v = acc[fc][i] + bv;
            if (EXPZ && bz) v = __builtin_amdgcn_exp2f(LOG2E2 * v);
            if (ADDQ) v += addend[row * N + col];
            if (OUTBF) Cb[row * N + col] = f2bf(v);
            else       Cf[row * N + col] = v;
        }
    }
}

// ---------------- raw scores: 2 q-rows per block, k-split --------------------
// Grid (8 kt, 256 qg) x 256 threads (4 waves). Wave handles rows k = kt*64 +
// wave + 4*i, i=0..15, computing BOTH q-rows per K load (halves L2 traffic,
// 4 independent rcp chains). w is pre-folded with -2; lane partial starts at
// lane's Wsum so the shuffle reduce yields Wsum - 2*sum in one pass.
__global__ __launch_bounds__(256) void score_k(
    const float* __restrict__ Qb, const float* __restrict__ Ek,
    const float* __restrict__ mask, const float* __restrict__ w_att,
    const float* __restrict__ b_att, float* __restrict__ scores)
{
    const int kt = blockIdx.x;          // 0..7
    const int q0 = blockIdx.y * 2;      // 0..510
    const int tid = threadIdx.x;
    const int lane = tid & 63, wave = tid >> 6;

    float qe0[3][4], qe1[3][4], wv[3][4];
    float Wsum = 0.f;
    #pragma unroll
    for (int jj = 0; jj < 3; ++jj) {
        float4 qa = *(const float4*)(Qb + q0 * D + 4 * lane + 256 * jj);
        float4 qb = *(const float4*)(Qb + (q0 + 1) * D + 4 * lane + 256 * jj);
        float4 wq = *(const float4*)(w_att + 4 * lane + 256 * jj);
        qe0[jj][0] = __builtin_amdgcn_exp2f(LOG2E2 * qa.x);
        qe0[jj][1] = __builtin_amdgcn_exp2f(LOG2E2 * qa.y);
        qe0[jj][2] = __builtin_amdgcn_exp2f(LOG2E2 * qa.z);
        qe0[jj][3] = __builtin_amdgcn_exp2f(LOG2E2 * qa.w);
        qe1[jj][0] = __builtin_amdgcn_exp2f(LOG2E2 * qb.x);
        qe1[jj][1] = __builtin_amdgcn_exp2f(LOG2E2 * qb.y);
        qe1[jj][2] = __builtin_amdgcn_exp2f(LOG2E2 * qb.z);
        qe1[jj][3] = __builtin_amdgcn_exp2f(LOG2E2 * qb.w);
        Wsum += wq.x + wq.y + wq.z + wq.w;
        wv[jj][0] = -2.f * wq.x; wv[jj][1] = -2.f * wq.y;
        wv[jj][2] = -2.f * wq.z; wv[jj][3] = -2.f * wq.w;
    }
    const float batt = b_att[0];
    const int kb0 = kt * 64 + wave;

    for (int i = 0; i < 16; ++i) {
        const int k = kb0 + 4 * i;
        const float4* K4 = (const float4*)(Ek + k * D) + lane;
        float s0 = Wsum, s1 = Wsum;
        #pragma unroll
        for (int jj = 0; jj < 3; ++jj) {
            float4 e = K4[64 * jj];
            s0 = fmaf(wv[jj][0], __builtin_amdgcn_rcpf(fmaf(qe0[jj][0], e.x, 1.f)), s0);
            s1 = fmaf(wv[jj][0], __builtin_amdgcn_rcpf(fmaf(qe1[jj][0], e.x, 1.f)), s1);
            s0 = fmaf(wv[jj][1], __builtin_amdgcn_rcpf(fmaf(qe0[jj][1], e.y, 1.f)), s0);
            s1 = fmaf(wv[jj][1], __builtin_amdgcn_rcpf(fmaf(qe1[jj][1], e.y, 1.f)), s1);
            s0 = fmaf(wv[jj][2], __builtin_amdgcn_rcpf(fmaf(qe0[jj][2], e.z, 1.f)), s0);
            s1 = fmaf(wv[jj][2], __builtin_amdgcn_rcpf(fmaf(qe1[jj][2], e.z, 1.f)), s1);
            s0 = fmaf(wv[jj][3], __builtin_amdgcn_rcpf(fmaf(qe0[jj][3], e.w, 1.f)), s0);
            s1 = fmaf(wv[jj][3], __builtin_amdgcn_rcpf(fmaf(qe1[jj][3], e.w, 1.f)), s1);
        }
        #pragma unroll
        for (int off = 32; off; off >>= 1) {
            s0 += __shfl_xor(s0, off);
            s1 += __shfl_xor(s1, off);
        }
        if (lane == 0) {
            const float mk = batt + mask[k];
            scores[q0 * L + k]       = s0 + mk;
            scores[(q0 + 1) * L + k] = s1 + mk;
        }
    }
}

// ---------------- softmax -> bf16 probs, 2 q-rows per block ------------------
__global__ __launch_bounds__(512) void softmax_probs(
    const float* __restrict__ scores, ushort* __restrict__ Pbf)
{
    __shared__ float redA[8], redB[8], redC[8], redD[8];
    const int q0 = blockIdx.x * 2;
    const int tid = threadIdx.x;
    const int lane = tid & 63, wave = tid >> 6;

    float v0 = scores[q0 * L + tid];
    float v1 = scores[(q0 + 1) * L + tid];

    float m0 = v0, m1 = v1;
    #pragma unroll
    for (int off = 32; off; off >>= 1) {
        m0 = fmaxf(m0, __shfl_xor(m0, off));
        m1 = fmaxf(m1, __shfl_xor(m1, off));
    }
    if (lane == 0) { redA[wave] = m0; redB[wave] = m1; }
    __syncthreads();
    float mm0 = redA[0], mm1 = redB[0];
    #pragma unroll
    for (int i = 1; i < 8; ++i) { mm0 = fmaxf(mm0, redA[i]); mm1 = fmaxf(mm1, redB[i]); }
    float e0 = __builtin_amdgcn_exp2f(LOG2E * (v0 - mm0));
    float e1 = __builtin_amdgcn_exp2f(LOG2E * (v1 - mm1));
    float s0 = e0, s1 = e1;
    #pragma unroll
    for (int off = 32; off; off >>= 1) {
        s0 += __shfl_xor(s0, off);
        s1 += __shfl_xor(s1, off);
    }
    if (lane == 0) { redC[wave] = s0; redD[wave] = s1; }
    __syncthreads();
    float t0 = redC[0], t1 = redD[0];
    #pragma unroll
    for (int i = 1; i < 8; ++i) { t0 += redC[i]; t1 += redD[i]; }
    Pbf[q0 * L + tid]       = f2bf(e0 * __builtin_amdgcn_rcpf(t0));
    Pbf[(q0 + 1) * L + tid] = f2bf(e1 * __builtin_amdgcn_rcpf(t1));
}

extern "C" void kernel_launch(void* const* d_in, const int* in_sizes, int n_in,
                              void* d_out, int out_size, void* d_ws, size_t ws_size,
                              hipStream_t stream) {
    const float* X     = (const float*)d_in[0];
    const float* mask  = (const float*)d_in[1];
    const float* Wq    = (const float*)d_in[2];
    const float* bq    = (const float*)d_in[3];
    const float* Wk    = (const float*)d_in[4];
    const float* bk    = (const float*)d_in[5];
    const float* w_att = (const float*)d_in[6];
    const float* b_att = (const float*)d_in[7];
    const float* Wt    = (const float*)d_in[8];
    const float* bt    = (const float*)d_in[9];
    float* out = (float*)d_out;

    const int LD = L * D, DD = D * D, LL = L * L;
    float*  Qb   = (float*)d_ws;          // [L*D] fp32 Q (score input + final addend)
    float*  Ek   = Qb + LD;               // [L*D] fp32 exp2(LOG2E2*(X@Wk+bk))
    ushort* Xbf  = (ushort*)(Ek + LD);    // [L*D] bf16 X
    ushort* XbfT = Xbf + LD;              // [D][L] bf16 X^T
    ushort* WqT  = XbfT + LD;             // [D][D]
    ushort* WkT  = WqT + DD;
    ushort* WtT  = WkT + DD;
    ushort* Pbf  = WtT + DD;              // [L][L] bf16 probs
    ushort* Wbf  = Pbf + LL;              // [L][D] bf16 weighted
    // scores scratch in d_out (1 MB of 1.57 MB), overwritten by final GEMM.
    float* scores = out;                  // [L*L]

    // prep: bf16 casts + transposes
    transpose_cast<<<dim3(D / 64, D / 64, 4), 256, 0, stream>>>(
        X, Wq, Wk, Wt, Xbf, XbfT, WqT, WkT, WtT);

    // Q = X@Wq + bq (fp32) ; Ek = exp2(LOG2E2*(X@Wk + bk)) (fp32), fused via z
    gemm_mfma<true, true, false, true, false><<<dim3(D / 64, L / 32, 2), 256, 0, stream>>>(
        Xbf, WqT, WkT, bq, bk, Qb, Ek, nullptr, nullptr, D);

    // raw scores: 2 q-rows per block
    score_k<<<dim3(8, L / 2), 256, 0, stream>>>(Qb, Ek, mask, w_att, b_att, scores);

    // softmax -> bf16 probs
    softmax_probs<<<dim3(L / 2), 512, 0, stream>>>(scores, Pbf);

    // weighted = probs @ X  (bf16 out)
    gemm_mfma<false, false, true, false, false><<<dim3(D / 64, L / 32, 1), 256, 0, stream>>>(
        Pbf, XbfT, nullptr, nullptr, nullptr, nullptr, nullptr, Wbf, nullptr, L);

    // out = weighted@Wt + bt + Q  (fp32)
    gemm_mfma<false, false, false, true, true><<<dim3(D / 64, L / 32, 1), 256, 0, stream>>>(
        Wbf, WtT, nullptr, bt, nullptr, out, nullptr, nullptr, Qb, D);
}